// Round 1
// 851.161 us; speedup vs baseline: 1.6308x; 1.6308x over previous
//
#include <hip/hip_runtime.h>
#include <hip/hip_bf16.h>
#include <stdint.h>

#define VOCAB 10000
#define HID   256
#define BATCH 32
#define STEPS 256

typedef __attribute__((ext_vector_type(8))) short short8;
typedef __attribute__((ext_vector_type(4))) float floatx4;

__device__ __forceinline__ float bf2f(unsigned short u) {
    union { unsigned int ui; float f; } v;
    v.ui = ((unsigned int)u) << 16;
    return v.f;
}

__device__ __forceinline__ unsigned short f2bf(float f) {
    union { float f; unsigned int ui; } v;
    v.f = f;
    unsigned int u = v.ui;
    unsigned int r = (u + 0x7FFFu + ((u >> 16) & 1u)) >> 16;  // RNE
    return (unsigned short)r;
}

// packed bf16x2 dot product: acc += lo(w)*lo(h) + hi(w)*hi(h)
#if __has_builtin(__builtin_amdgcn_fdot2_f32_bf16)
typedef __bf16 bf16x2 __attribute__((ext_vector_type(2)));
__device__ __forceinline__ float dot2(unsigned int w, unsigned int h, float acc) {
    union { unsigned int u; bf16x2 v; } a, b;
    a.u = w; b.u = h;
    return __builtin_amdgcn_fdot2_f32_bf16(a.v, b.v, acc, false);
}
#else
__device__ __forceinline__ float dot2(unsigned int w, unsigned int h, float acc) {
    union { unsigned int u; float f; } w0, w1, h0, h1;
    w0.u = w << 16; w1.u = w & 0xFFFF0000u;
    h0.u = h << 16; h1.u = h & 0xFFFF0000u;
    acc = fmaf(w0.f, h0.f, acc);
    acc = fmaf(w1.f, h1.f, acc);
    return acc;
}
#endif

__device__ __forceinline__ float sigmoidf_(float x) {
    return __builtin_amdgcn_rcpf(1.0f + __expf(-x));
}
__device__ __forceinline__ float tanhf_(float x) {
    // 1 - 2/(exp(2x)+1); correct limits at +-inf with v_exp
    float e = __expf(2.0f * x);
    return 1.0f - 2.0f * __builtin_amdgcn_rcpf(e + 1.0f);
}

// ---------------------------------------------------------------------------
// prep_w: Whz/Whr/Whh f32[256][256] -> Wsw[g][p4(32)][j(256)][m(8)] bf16
//   Wsw entry (g,p4,j,m) = W_g[p4*8+m][j]   (k-pairs contiguous per column j)
// grid (3, 256), 256 thr. Reads coalesced.
// ---------------------------------------------------------------------------
__global__ void prep_w(const float* __restrict__ Wz, const float* __restrict__ Wr,
                       const float* __restrict__ Wh, unsigned short* __restrict__ out) {
    int g = blockIdx.x, k = blockIdx.y, j = threadIdx.x;
    const float* W = (g == 0) ? Wz : (g == 1) ? Wr : Wh;
    float v = W[k * HID + j];
    int p4 = k >> 3, m = k & 7;
    out[(((size_t)g * 32 + p4) * HID + j) * 8 + m] = f2bf(v);
}

// ---------------------------------------------------------------------------
// prep_b: Whq f32[256][10000] -> B-fragment buffer for mfma_16x16x32_bf16
//   bfr[nt(625)][kc(8)][lane(64)][jj(8)] = Whq[kc*32 + (lane>>4)*8 + jj][nt*16 + (lane&15)]
// grid (40, 256), 256 thr. Reads coalesced, writes scattered (one-time).
// ---------------------------------------------------------------------------
__global__ void prep_b(const float* __restrict__ Whq, unsigned short* __restrict__ bfr) {
    int k = blockIdx.y;
    int n = blockIdx.x * 256 + threadIdx.x;
    if (n >= VOCAB) return;
    float v = Whq[(size_t)k * VOCAB + n];
    int nt = n >> 4, l15 = n & 15;
    int kc = k >> 5, kr = k & 31;
    int quad = kr >> 3, jj = kr & 7;
    int lane = quad * 16 + l15;
    bfr[(((size_t)nt * 8 + kc) * 64 + lane) * 8 + jj] = f2bf(v);
}

// ---------------------------------------------------------------------------
// gru_rec: 32 blocks (one batch row) x 512 threads (8 waves).
//   Threads 0..255  (group A, col j): z-gate full-K dot, then h-gate K-low half,
//                                     activations/blend, owns the f32 h chain.
//   Threads 256..511 (group B, col j): r-gate full-K dot, rh, h-gate K-high half.
// Weights: bf16 pre-swizzled (Wsw), hoisted into VGPRs BEFORE the t-loop
//   (192 VGPRs/thread of loop-invariant weights -> zero L2 weight traffic
//    per step; previous version re-streamed 384 KB/CU/step from L2, which
//    was the per-step bottleneck).
// h state: bf16 in LDS (broadcast b128 reads feed dot2 pairs).
// x one-hot projections: rows gathered into LDS, double-buffered, prefetched.
// ---------------------------------------------------------------------------
__global__ __launch_bounds__(512, 1) void gru_rec(
    const int* __restrict__ X, const float* __restrict__ H0,
    const float* __restrict__ Wxz, const float* __restrict__ Wxr,
    const float* __restrict__ Wxh,
    const float* __restrict__ bz, const float* __restrict__ br,
    const float* __restrict__ bh,
    const unsigned short* __restrict__ Wsw,
    unsigned short* __restrict__ hist,   // [STEPS*BATCH][HID] bf16
    float* __restrict__ h_final)         // [BATCH][HID] f32
{
    const int b = blockIdx.x;
    const int tid = threadIdx.x;
    const bool isA = tid < HID;
    const int j = isA ? tid : tid - HID;

    __shared__ __align__(16) unsigned short hbuf[HID];
    __shared__ __align__(16) unsigned short rhbuf[HID];
    __shared__ float part[HID];
    __shared__ float xrow[2][3][HID];
    __shared__ int Xl[STEPS];

    const uint4* wA = (const uint4*)Wsw + (size_t)(isA ? 0 : 1) * 32 * HID + j; // z or r
    const uint4* wH = (const uint4*)Wsw + (size_t)2 * 32 * HID + j;             // h

    float h_my = H0[b * HID + j];
    float bias = isA ? bz[j] : br[j];
    float bhj  = isA ? bh[j] : 0.0f;

    // ---- hoist loop-invariant weights into registers (static indexing only) ----
    uint4 wreg[32];          // full-K column of W_hz (A) / W_hr (B): 128 VGPRs
    #pragma unroll
    for (int i = 0; i < 32; ++i) wreg[i] = wA[i * HID];

    const int i0 = isA ? 0 : 16;
    uint4 whreg[16];         // K-half column of W_hh: 64 VGPRs
    #pragma unroll
    for (int i = 0; i < 16; ++i) whreg[i] = wH[(i0 + i) * HID];

    if (isA) { hbuf[j] = f2bf(h_my); Xl[j] = X[b * STEPS + j]; }
    __syncthreads();

    {   // initial x-row gather for t=0
        int x0 = Xl[0];
        if (isA) {
            xrow[0][0][j] = Wxz[(size_t)x0 * HID + j];
            xrow[0][2][j] = Wxh[(size_t)x0 * HID + j];
        } else {
            xrow[0][1][j] = Wxr[(size_t)x0 * HID + j];
        }
    }
    __syncthreads();

    float z = 0.0f;

    for (int t = 0; t < STEPS; ++t) {
        const int cur = t & 1, nxt = cur ^ 1;

        // prefetch next step's x-projection rows (wraps harmlessly at t=255)
        const int xn = Xl[(t + 1) & (STEPS - 1)];
        float p0 = 0.f, p1 = 0.f;
        if (isA) {
            p0 = Wxz[(size_t)xn * HID + j];
            p1 = Wxh[(size_t)xn * HID + j];
        } else {
            p0 = Wxr[(size_t)xn * HID + j];
        }

        // z-gate (A) / r-gate (B): full-K dot over h pairs, weights from VGPRs
        float acc;
        {
            const uint4* hp = (const uint4*)hbuf;
            float a0 = 0.f, a1 = 0.f, a2 = 0.f, a3 = 0.f;
            #pragma unroll
            for (int i = 0; i < 32; ++i) {
                uint4 hv = hp[i];
                a0 = dot2(wreg[i].x, hv.x, a0);
                a1 = dot2(wreg[i].y, hv.y, a1);
                a2 = dot2(wreg[i].z, hv.z, a2);
                a3 = dot2(wreg[i].w, hv.w, a3);
            }
            acc = (a0 + a1) + (a2 + a3);
        }

        if (isA) {
            z = sigmoidf_(acc + xrow[cur][0][j] + bias);
            xrow[nxt][0][j] = p0;
            xrow[nxt][2][j] = p1;
        } else {
            float r = sigmoidf_(acc + xrow[cur][1][j] + bias);
            rhbuf[j] = f2bf(r * h_my);
            xrow[nxt][1][j] = p0;
        }
        __syncthreads();  // B1: rhbuf + xrow[nxt] published

        // h-gate: K split between groups (A: pairs 0..63, B: 64..127)
        float acch;
        {
            const uint4* rp = (const uint4*)rhbuf;
            float a0 = 0.f, a1 = 0.f, a2 = 0.f, a3 = 0.f;
            #pragma unroll
            for (int i = 0; i < 16; ++i) {
                uint4 hv = rp[i0 + i];
                a0 = dot2(whreg[i].x, hv.x, a0);
                a1 = dot2(whreg[i].y, hv.y, a1);
                a2 = dot2(whreg[i].z, hv.z, a2);
                a3 = dot2(whreg[i].w, hv.w, a3);
            }
            acch = (a0 + a1) + (a2 + a3);
        }
        if (!isA) part[j] = acch;
        __syncthreads();  // B2: h-gate partials published

        if (isA) {
            float hpre = acch + part[j] + xrow[cur][2][j] + bhj;
            float ht = tanhf_(hpre);
            float hn = z * h_my + (1.0f - z) * ht;
            h_my = hn;
            unsigned short hb = f2bf(hn);
            hbuf[j] = hb;
            hist[((size_t)t * BATCH + b) * HID + j] = hb;
        }
        __syncthreads();  // B3: hbuf published

        if (!isA) h_my = bf2f(hbuf[j]);  // B's h copy (bf16-rounded, used only for rh)
    }

    if (isA) h_final[b * HID + j] = h_my;
}

// ---------------------------------------------------------------------------
// proj: C[8192][10000] = A[8192][256](bf16) @ B[256][10000](bf16) + bq, f32 out
// MFMA 16x16x32, no LDS. Block: 256 thr (4 waves), BM=128 (8 m-tiles),
// 4 n-tiles per wave (block covers 16 n-tiles). B from pre-swizzled frag buf
// (coalesced dwordx4); A straight from bf16 h_hist (16B/lane, 64B/quad-col).
// ---------------------------------------------------------------------------
__global__ __launch_bounds__(256, 2) void proj(
    const unsigned short* __restrict__ Abf,  // h_hist [8192][256] bf16
    const unsigned short* __restrict__ Bfr,  // frag buffer [625][8][64][8]
    const float* __restrict__ bq,
    float* __restrict__ C)
{
    const int tid  = threadIdx.x;
    const int wave = tid >> 6;
    const int lane = tid & 63;
    const int l15  = lane & 15;
    const int quad = lane >> 4;

    const int nb = blockIdx.x;   // 0..39
    const int mb = blockIdx.y;   // 0..63
    const int m0 = mb * 128;
    const int nt0 = nb * 16 + wave * 4;

    floatx4 acc[8][4];
    #pragma unroll
    for (int i = 0; i < 8; ++i)
        #pragma unroll
        for (int q = 0; q < 4; ++q)
            acc[i][q] = (floatx4)0.0f;

    // clamp n-tiles for loads in the ragged tail block (stores are guarded)
    int ntc[4];
    #pragma unroll
    for (int q = 0; q < 4; ++q) {
        int nt = nt0 + q;
        ntc[q] = (nt < 625) ? nt : 624;
    }

    for (int kc = 0; kc < 8; ++kc) {
        short8 a[8];
        #pragma unroll
        for (int mt = 0; mt < 8; ++mt) {
            const unsigned short* ap =
                Abf + (size_t)(m0 + mt * 16 + l15) * HID + kc * 32 + quad * 8;
            a[mt] = *(const short8*)ap;
        }
        short8 bfrg[4];
        #pragma unroll
        for (int q = 0; q < 4; ++q) {
            const unsigned short* bp =
                Bfr + ((((size_t)ntc[q] * 8 + kc) * 64) + lane) * 8;
            bfrg[q] = *(const short8*)bp;
        }
        #pragma unroll
        for (int mt = 0; mt < 8; ++mt)
            #pragma unroll
            for (int q = 0; q < 4; ++q)
                acc[mt][q] = __builtin_amdgcn_mfma_f32_16x16x32_bf16(
                    a[mt], bfrg[q], acc[mt][q], 0, 0, 0);
    }

    // epilogue: bias + store (C/D layout: col = lane&15, row = quad*4 + reg)
    #pragma unroll
    for (int q = 0; q < 4; ++q) {
        int nt = nt0 + q;
        if (nt >= 625) continue;
        int col = nt * 16 + l15;
        float bqv = bq[col];
        #pragma unroll
        for (int mt = 0; mt < 8; ++mt) {
            int rowb = m0 + mt * 16 + quad * 4;
            #pragma unroll
            for (int r = 0; r < 4; ++r) {
                C[(size_t)(rowb + r) * VOCAB + col] = acc[mt][q][r] + bqv;
            }
        }
    }
}

// ---------------------------------------------------------------------------
extern "C" void kernel_launch(void* const* d_in, const int* in_sizes, int n_in,
                              void* d_out, int out_size, void* d_ws, size_t ws_size,
                              hipStream_t stream) {
    const int*   X   = (const int*)  d_in[0];
    const float* H0  = (const float*)d_in[1];
    const float* Wxz = (const float*)d_in[2];
    const float* Whz = (const float*)d_in[3];
    const float* bz  = (const float*)d_in[4];
    const float* Wxr = (const float*)d_in[5];
    const float* Whr = (const float*)d_in[6];
    const float* br  = (const float*)d_in[7];
    const float* Wxh = (const float*)d_in[8];
    const float* Whh = (const float*)d_in[9];
    const float* bh  = (const float*)d_in[10];
    const float* Whq = (const float*)d_in[11];
    const float* bq  = (const float*)d_in[12];

    float* out     = (float*)d_out;
    float* h_final = out + (size_t)STEPS * BATCH * VOCAB;

    // ws layout (ushorts): Wsw[196608] | Bfr[2560000] | hist[2097152]  = 9.26 MB
    unsigned short* wsw  = (unsigned short*)d_ws;
    unsigned short* bfr  = wsw + 196608;
    unsigned short* hist = bfr + 2560000;

    prep_w<<<dim3(3, 256), 256, 0, stream>>>(Whz, Whr, Whh, wsw);
    prep_b<<<dim3(40, 256), 256, 0, stream>>>(Whq, bfr);
    gru_rec<<<BATCH, 512, 0, stream>>>(X, H0, Wxz, Wxr, Wxh, bz, br, bh,
                                       wsw, hist, h_final);
    proj<<<dim3(40, 64), 256, 0, stream>>>(hist, bfr, bq, out);
}

// Round 2
// 827.313 us; speedup vs baseline: 1.6779x; 1.0288x over previous
//
#include <hip/hip_runtime.h>
#include <hip/hip_bf16.h>
#include <stdint.h>

#define VOCAB 10000
#define HID   256
#define BATCH 32
#define STEPS 256

typedef __attribute__((ext_vector_type(8))) short short8;
typedef __attribute__((ext_vector_type(4))) float floatx4;

__device__ __forceinline__ float bf2f(unsigned short u) {
    union { unsigned int ui; float f; } v;
    v.ui = ((unsigned int)u) << 16;
    return v.f;
}

__device__ __forceinline__ unsigned short f2bf(float f) {
    union { float f; unsigned int ui; } v;
    v.f = f;
    unsigned int u = v.ui;
    unsigned int r = (u + 0x7FFFu + ((u >> 16) & 1u)) >> 16;  // RNE
    return (unsigned short)r;
}

// packed bf16x2 dot product: acc += lo(w)*lo(h) + hi(w)*hi(h)
#if __has_builtin(__builtin_amdgcn_fdot2_f32_bf16)
typedef __bf16 bf16x2 __attribute__((ext_vector_type(2)));
__device__ __forceinline__ float dot2(unsigned int w, unsigned int h, float acc) {
    union { unsigned int u; bf16x2 v; } a, b;
    a.u = w; b.u = h;
    return __builtin_amdgcn_fdot2_f32_bf16(a.v, b.v, acc, false);
}
#else
__device__ __forceinline__ float dot2(unsigned int w, unsigned int h, float acc) {
    union { unsigned int u; float f; } w0, w1, h0, h1;
    w0.u = w << 16; w1.u = w & 0xFFFF0000u;
    h0.u = h << 16; h1.u = h & 0xFFFF0000u;
    acc = fmaf(w0.f, h0.f, acc);
    acc = fmaf(w1.f, h1.f, acc);
    return acc;
}
#endif

__device__ __forceinline__ float sigmoidf_(float x) {
    return __builtin_amdgcn_rcpf(1.0f + __expf(-x));
}
__device__ __forceinline__ float tanhf_(float x) {
    // 1 - 2/(exp(2x)+1); correct limits at +-inf with v_exp
    float e = __expf(2.0f * x);
    return 1.0f - 2.0f * __builtin_amdgcn_rcpf(e + 1.0f);
}

// ---------------------------------------------------------------------------
// prep_w: Whz/Whr/Whh f32[256][256] -> Wsw[g][p4(32)][j(256)][m(8)] bf16
//   Wsw entry (g,p4,j,m) = W_g[p4*8+m][j]
// grid (3, 32), 256 thr. Coalesced f32 row reads; contiguous 16B short8 writes.
// ---------------------------------------------------------------------------
__global__ void prep_w(const float* __restrict__ Wz, const float* __restrict__ Wr,
                       const float* __restrict__ Wh, unsigned short* __restrict__ out) {
    int g = blockIdx.x, p4 = blockIdx.y, j = threadIdx.x;
    const float* W = (g == 0) ? Wz : (g == 1) ? Wr : Wh;
    union { unsigned short us[8]; short8 v; } pk;
    #pragma unroll
    for (int m = 0; m < 8; ++m)
        pk.us[m] = f2bf(W[(p4 * 8 + m) * HID + j]);
    *(short8*)(out + (((size_t)g * 32 + p4) * HID + j) * 8) = pk.v;
}

// ---------------------------------------------------------------------------
// prep_b: Whq f32[256][10000] -> B-fragment buffer for mfma_16x16x32_bf16
//   bfr[nt(625)][kc(8)][lane(64)][jj(8)] = Whq[kc*32 + (lane>>4)*8 + jj][nt*16 + (lane&15)]
// grid (40, 8): x = 256-col group, y = kc. LDS transpose:
//   coalesced f32 tile loads -> LDS -> fully-contiguous 16B short8 writes.
// ---------------------------------------------------------------------------
__global__ void prep_b(const float* __restrict__ Whq, unsigned short* __restrict__ bfr) {
    __shared__ float lds[32][257];   // +1 pad breaks bank aliasing on the gather
    const int nb = blockIdx.x;       // 0..39  (256 cols each)
    const int kc = blockIdx.y;       // 0..7   (32 k-rows each)
    const int tid = threadIdx.x;
    const int n0 = nb * 256;

    // load 32 rows x 256 cols, coalesced (1KB per row per wavefront-group)
    #pragma unroll 4
    for (int kk = 0; kk < 32; ++kk) {
        int n = n0 + tid;
        float v = (n < VOCAB) ? Whq[(size_t)(kc * 32 + kk) * VOCAB + n] : 0.0f;
        lds[kk][tid] = v;
    }
    __syncthreads();

    // write 16 nt-tiles: per nt, 64 lanes x 16B contiguous (1KB blocks)
    const int lane = tid & 63;
    const int wq   = tid >> 6;       // 0..3
    const int quad = lane >> 4, l15 = lane & 15;
    #pragma unroll
    for (int ntp = 0; ntp < 4; ++ntp) {
        int nt_local = ntp * 4 + wq;
        int nt = nb * 16 + nt_local;
        if (nt >= 625) continue;
        union { unsigned short us[8]; short8 v; } pk;
        #pragma unroll
        for (int jj = 0; jj < 8; ++jj)
            pk.us[jj] = f2bf(lds[quad * 8 + jj][nt_local * 16 + l15]);
        *(short8*)(bfr + (((size_t)nt * 8 + kc) * 64 + lane) * 8) = pk.v;
    }
}

// ---------------------------------------------------------------------------
// gru_rec: 32 blocks (one batch row) x 512 threads (8 waves).
//   Threads 0..255  (group A, col j): z-gate full-K dot, then h-gate K-low half,
//                                     activations/blend, owns the f32 h chain.
//   Threads 256..511 (group B, col j): r-gate full-K dot, rh, h-gate K-high half.
// Weights: bf16 pre-swizzled (Wsw), hoisted into VGPRs BEFORE the t-loop
//   (loop-invariant -> zero per-step L2 weight traffic).
// h state: bf16 in LDS (broadcast b128 reads feed dot2 pairs).
// x one-hot projections: rows gathered into LDS, double-buffered, prefetched.
// ---------------------------------------------------------------------------
__global__ __launch_bounds__(512, 1) void gru_rec(
    const int* __restrict__ X, const float* __restrict__ H0,
    const float* __restrict__ Wxz, const float* __restrict__ Wxr,
    const float* __restrict__ Wxh,
    const float* __restrict__ bz, const float* __restrict__ br,
    const float* __restrict__ bh,
    const unsigned short* __restrict__ Wsw,
    unsigned short* __restrict__ hist,   // [STEPS*BATCH][HID] bf16
    float* __restrict__ h_final)         // [BATCH][HID] f32
{
    const int b = blockIdx.x;
    const int tid = threadIdx.x;
    const bool isA = tid < HID;
    const int j = isA ? tid : tid - HID;

    __shared__ __align__(16) unsigned short hbuf[HID];
    __shared__ __align__(16) unsigned short rhbuf[HID];
    __shared__ float part[HID];
    __shared__ float xrow[2][3][HID];
    __shared__ int Xl[STEPS];

    const uint4* wA = (const uint4*)Wsw + (size_t)(isA ? 0 : 1) * 32 * HID + j; // z or r
    const uint4* wH = (const uint4*)Wsw + (size_t)2 * 32 * HID + j;             // h

    float h_my = H0[b * HID + j];
    float bias = isA ? bz[j] : br[j];
    float bhj  = isA ? bh[j] : 0.0f;

    // ---- hoist loop-invariant weights into registers (static indexing only) ----
    uint4 wreg[32];          // full-K column of W_hz (A) / W_hr (B)
    #pragma unroll
    for (int i = 0; i < 32; ++i) wreg[i] = wA[i * HID];

    const int i0 = isA ? 0 : 16;
    uint4 whreg[16];         // K-half column of W_hh
    #pragma unroll
    for (int i = 0; i < 16; ++i) whreg[i] = wH[(i0 + i) * HID];

    if (isA) { hbuf[j] = f2bf(h_my); Xl[j] = X[b * STEPS + j]; }
    __syncthreads();

    {   // initial x-row gather for t=0
        int x0 = Xl[0];
        if (isA) {
            xrow[0][0][j] = Wxz[(size_t)x0 * HID + j];
            xrow[0][2][j] = Wxh[(size_t)x0 * HID + j];
        } else {
            xrow[0][1][j] = Wxr[(size_t)x0 * HID + j];
        }
    }
    __syncthreads();

    float z = 0.0f;

    for (int t = 0; t < STEPS; ++t) {
        const int cur = t & 1, nxt = cur ^ 1;

        // prefetch next step's x-projection rows (wraps harmlessly at t=255)
        const int xn = Xl[(t + 1) & (STEPS - 1)];
        float p0 = 0.f, p1 = 0.f;
        if (isA) {
            p0 = Wxz[(size_t)xn * HID + j];
            p1 = Wxh[(size_t)xn * HID + j];
        } else {
            p0 = Wxr[(size_t)xn * HID + j];
        }

        // z-gate (A) / r-gate (B): full-K dot over h pairs, weights from VGPRs
        float acc;
        {
            const uint4* hp = (const uint4*)hbuf;
            float a0 = 0.f, a1 = 0.f, a2 = 0.f, a3 = 0.f;
            #pragma unroll
            for (int i = 0; i < 32; ++i) {
                uint4 hv = hp[i];
                a0 = dot2(wreg[i].x, hv.x, a0);
                a1 = dot2(wreg[i].y, hv.y, a1);
                a2 = dot2(wreg[i].z, hv.z, a2);
                a3 = dot2(wreg[i].w, hv.w, a3);
            }
            acc = (a0 + a1) + (a2 + a3);
        }

        if (isA) {
            z = sigmoidf_(acc + xrow[cur][0][j] + bias);
            xrow[nxt][0][j] = p0;
            xrow[nxt][2][j] = p1;
        } else {
            float r = sigmoidf_(acc + xrow[cur][1][j] + bias);
            rhbuf[j] = f2bf(r * h_my);
            xrow[nxt][1][j] = p0;
        }
        __syncthreads();  // B1: rhbuf + xrow[nxt] published

        // h-gate: K split between groups (A: pairs 0..63, B: 64..127)
        float acch;
        {
            const uint4* rp = (const uint4*)rhbuf;
            float a0 = 0.f, a1 = 0.f, a2 = 0.f, a3 = 0.f;
            #pragma unroll
            for (int i = 0; i < 16; ++i) {
                uint4 hv = rp[i0 + i];
                a0 = dot2(whreg[i].x, hv.x, a0);
                a1 = dot2(whreg[i].y, hv.y, a1);
                a2 = dot2(whreg[i].z, hv.z, a2);
                a3 = dot2(whreg[i].w, hv.w, a3);
            }
            acch = (a0 + a1) + (a2 + a3);
        }
        if (!isA) part[j] = acch;
        __syncthreads();  // B2: h-gate partials published

        if (isA) {
            float hpre = acch + part[j] + xrow[cur][2][j] + bhj;
            float ht = tanhf_(hpre);
            float hn = z * h_my + (1.0f - z) * ht;
            h_my = hn;
            unsigned short hb = f2bf(hn);
            hbuf[j] = hb;
            hist[((size_t)t * BATCH + b) * HID + j] = hb;
        }
        __syncthreads();  // B3: hbuf published

        if (!isA) h_my = bf2f(hbuf[j]);  // B's h copy (bf16-rounded, used only for rh)
    }

    if (isA) h_final[b * HID + j] = h_my;
}

// ---------------------------------------------------------------------------
// proj: C[8192][10000] = A[8192][256](bf16) @ B[256][10000](bf16) + bq, f32 out
// MFMA 16x16x32, no LDS. Block: 256 thr (4 waves), BM=128 (8 m-tiles),
// 4 n-tiles per wave.
//  * SWAPPED operands: mfma(bfrg, a, acc) computes the transposed tile with the
//    same fragment data (A/B layouts are mutual transposes) -> each lane holds
//    4 CONSECUTIVE columns -> float4 stores (32 instrs/thread, full lines).
//  * XCD-locality swizzle (1-D grid 2560): xcd = orig&7 owns 5 nb-columns x all
//    64 mb (mb ascending). Per-XCD L2 working set = 0.65MB B-slice (resident)
//    + sliding ~0.8MB A window -> L3 reads drop from ~500MB to ~40MB.
// ---------------------------------------------------------------------------
__global__ __launch_bounds__(256, 2) void proj(
    const unsigned short* __restrict__ Abf,  // h_hist [8192][256] bf16
    const unsigned short* __restrict__ Bfr,  // frag buffer [625][8][64][8]
    const float* __restrict__ bq,
    float* __restrict__ C)
{
    const int tid  = threadIdx.x;
    const int wave = tid >> 6;
    const int lane = tid & 63;
    const int l15  = lane & 15;
    const int quad = lane >> 4;

    // XCD-aware decode: blocks on one XCD share a 5-nb B-slice, sweep mb.
    const int orig = blockIdx.x;        // 0..2559
    const int xcd  = orig & 7;
    const int idx  = orig >> 3;         // 0..319
    const int mb   = idx / 5;           // 0..63
    const int nb   = xcd * 5 + (idx % 5);  // 0..39

    const int m0 = mb * 128;
    const int nt0 = nb * 16 + wave * 4;

    floatx4 acc[8][4];
    #pragma unroll
    for (int i = 0; i < 8; ++i)
        #pragma unroll
        for (int q = 0; q < 4; ++q)
            acc[i][q] = (floatx4)0.0f;

    // clamp n-tiles for loads in the ragged tail block (stores are guarded)
    int ntc[4];
    #pragma unroll
    for (int q = 0; q < 4; ++q) {
        int nt = nt0 + q;
        ntc[q] = (nt < 625) ? nt : 624;
    }

    for (int kc = 0; kc < 8; ++kc) {
        short8 a[8];
        #pragma unroll
        for (int mt = 0; mt < 8; ++mt) {
            const unsigned short* ap =
                Abf + (size_t)(m0 + mt * 16 + l15) * HID + kc * 32 + quad * 8;
            a[mt] = *(const short8*)ap;
        }
        short8 bfrg[4];
        #pragma unroll
        for (int q = 0; q < 4; ++q) {
            const unsigned short* bp =
                Bfr + ((((size_t)ntc[q] * 8 + kc) * 64) + lane) * 8;
            bfrg[q] = *(const short8*)bp;
        }
        // operands SWAPPED: lane now holds C[m0+mt*16+l15][nt*16+quad*4 + r]
        #pragma unroll
        for (int mt = 0; mt < 8; ++mt)
            #pragma unroll
            for (int q = 0; q < 4; ++q)
                acc[mt][q] = __builtin_amdgcn_mfma_f32_16x16x32_bf16(
                    bfrg[q], a[mt], acc[mt][q], 0, 0, 0);
    }

    // epilogue: bias + float4 stores (4 consecutive cols per lane)
    floatx4 bq4[4];
    #pragma unroll
    for (int q = 0; q < 4; ++q) {
        int nt = nt0 + q;
        bq4[q] = (nt < 625) ? *(const floatx4*)(bq + nt * 16 + quad * 4)
                            : (floatx4)0.0f;
    }
    #pragma unroll
    for (int mt = 0; mt < 8; ++mt) {
        const size_t rowoff = (size_t)(m0 + mt * 16 + l15) * VOCAB;
        #pragma unroll
        for (int q = 0; q < 4; ++q) {
            int nt = nt0 + q;
            if (nt >= 625) continue;
            floatx4 v = acc[mt][q] + bq4[q];
            *(floatx4*)(C + rowoff + nt * 16 + quad * 4) = v;
        }
    }
}

// ---------------------------------------------------------------------------
extern "C" void kernel_launch(void* const* d_in, const int* in_sizes, int n_in,
                              void* d_out, int out_size, void* d_ws, size_t ws_size,
                              hipStream_t stream) {
    const int*   X   = (const int*)  d_in[0];
    const float* H0  = (const float*)d_in[1];
    const float* Wxz = (const float*)d_in[2];
    const float* Whz = (const float*)d_in[3];
    const float* bz  = (const float*)d_in[4];
    const float* Wxr = (const float*)d_in[5];
    const float* Whr = (const float*)d_in[6];
    const float* br  = (const float*)d_in[7];
    const float* Wxh = (const float*)d_in[8];
    const float* Whh = (const float*)d_in[9];
    const float* bh  = (const float*)d_in[10];
    const float* Whq = (const float*)d_in[11];
    const float* bq  = (const float*)d_in[12];

    float* out     = (float*)d_out;
    float* h_final = out + (size_t)STEPS * BATCH * VOCAB;

    // ws layout (ushorts): Wsw[196608] | Bfr[2560000] | hist[2097152]  = 9.26 MB
    unsigned short* wsw  = (unsigned short*)d_ws;
    unsigned short* bfr  = wsw + 196608;
    unsigned short* hist = bfr + 2560000;

    prep_w<<<dim3(3, 32), 256, 0, stream>>>(Whz, Whr, Whh, wsw);
    prep_b<<<dim3(40, 8), 256, 0, stream>>>(Whq, bfr);
    gru_rec<<<BATCH, 512, 0, stream>>>(X, H0, Wxz, Wxr, Wxh, bz, br, bh,
                                       wsw, hist, h_final);
    proj<<<2560, 256, 0, stream>>>(hist, bfr, bq, out);
}

// Round 3
// 809.460 us; speedup vs baseline: 1.7149x; 1.0221x over previous
//
#include <hip/hip_runtime.h>
#include <hip/hip_bf16.h>
#include <stdint.h>

#define VOCAB 10000
#define HID   256
#define BATCH 32
#define STEPS 256

typedef __attribute__((ext_vector_type(8))) short short8;
typedef __attribute__((ext_vector_type(4))) float floatx4;

__device__ __forceinline__ float bf2f(unsigned short u) {
    union { unsigned int ui; float f; } v;
    v.ui = ((unsigned int)u) << 16;
    return v.f;
}

__device__ __forceinline__ unsigned short f2bf(float f) {
    union { float f; unsigned int ui; } v;
    v.f = f;
    unsigned int u = v.ui;
    unsigned int r = (u + 0x7FFFu + ((u >> 16) & 1u)) >> 16;  // RNE
    return (unsigned short)r;
}

// packed bf16x2 dot product: acc += lo(w)*lo(h) + hi(w)*hi(h)
#if __has_builtin(__builtin_amdgcn_fdot2_f32_bf16)
typedef __bf16 bf16x2 __attribute__((ext_vector_type(2)));
__device__ __forceinline__ float dot2(unsigned int w, unsigned int h, float acc) {
    union { unsigned int u; bf16x2 v; } a, b;
    a.u = w; b.u = h;
    return __builtin_amdgcn_fdot2_f32_bf16(a.v, b.v, acc, false);
}
#else
__device__ __forceinline__ float dot2(unsigned int w, unsigned int h, float acc) {
    union { unsigned int u; float f; } w0, w1, h0, h1;
    w0.u = w << 16; w1.u = w & 0xFFFF0000u;
    h0.u = h << 16; h1.u = h & 0xFFFF0000u;
    acc = fmaf(w0.f, h0.f, acc);
    acc = fmaf(w1.f, h1.f, acc);
    return acc;
}
#endif

__device__ __forceinline__ float sigmoidf_(float x) {
    return __builtin_amdgcn_rcpf(1.0f + __expf(-x));
}
__device__ __forceinline__ float tanhf_(float x) {
    // 1 - 2/(exp(2x)+1); correct limits at +-inf with v_exp
    float e = __expf(2.0f * x);
    return 1.0f - 2.0f * __builtin_amdgcn_rcpf(e + 1.0f);
}

// ---------------------------------------------------------------------------
// prep_w: Whz/Whr/Whh f32[256][256] -> Wsw[g][p4(32)][j(256)][m(8)] bf16
// grid (3, 32), 256 thr. Coalesced f32 row reads; contiguous 16B short8 writes.
// ---------------------------------------------------------------------------
__global__ void prep_w(const float* __restrict__ Wz, const float* __restrict__ Wr,
                       const float* __restrict__ Wh, unsigned short* __restrict__ out) {
    int g = blockIdx.x, p4 = blockIdx.y, j = threadIdx.x;
    const float* W = (g == 0) ? Wz : (g == 1) ? Wr : Wh;
    union { unsigned short us[8]; short8 v; } pk;
    #pragma unroll
    for (int m = 0; m < 8; ++m)
        pk.us[m] = f2bf(W[(p4 * 8 + m) * HID + j]);
    *(short8*)(out + (((size_t)g * 32 + p4) * HID + j) * 8) = pk.v;
}

// ---------------------------------------------------------------------------
// prep_b: Whq f32[256][10000] -> B-fragment buffer for mfma_16x16x32_bf16
//   bfr[nt(625)][kc(8)][lane(64)][jj(8)] = Whq[kc*32 + (lane>>4)*8 + jj][nt*16 + (lane&15)]
// grid (40, 8). LDS transpose: coalesced loads -> contiguous 16B short8 writes.
// ---------------------------------------------------------------------------
__global__ void prep_b(const float* __restrict__ Whq, unsigned short* __restrict__ bfr) {
    __shared__ float lds[32][257];   // +1 pad breaks bank aliasing on the gather
    const int nb = blockIdx.x;       // 0..39  (256 cols each)
    const int kc = blockIdx.y;       // 0..7   (32 k-rows each)
    const int tid = threadIdx.x;
    const int n0 = nb * 256;

    #pragma unroll 4
    for (int kk = 0; kk < 32; ++kk) {
        int n = n0 + tid;
        float v = (n < VOCAB) ? Whq[(size_t)(kc * 32 + kk) * VOCAB + n] : 0.0f;
        lds[kk][tid] = v;
    }
    __syncthreads();

    const int lane = tid & 63;
    const int wq   = tid >> 6;       // 0..3
    const int quad = lane >> 4, l15 = lane & 15;
    #pragma unroll
    for (int ntp = 0; ntp < 4; ++ntp) {
        int nt_local = ntp * 4 + wq;
        int nt = nb * 16 + nt_local;
        if (nt >= 625) continue;
        union { unsigned short us[8]; short8 v; } pk;
        #pragma unroll
        for (int jj = 0; jj < 8; ++jj)
            pk.us[jj] = f2bf(lds[quad * 8 + jj][nt_local * 16 + l15]);
        *(short8*)(bfr + (((size_t)nt * 8 + kc) * 64 + lane) * 8) = pk.v;
    }
}

// ---------------------------------------------------------------------------
// prep_a: hist[8192][256] bf16 -> A-fragment buffer Afr[MT(512)][kc(8)][lane(64)][8]
//   Afr[MT][kc][lane][jj] = hist[MT*16 + (lane&15)][kc*32 + (lane>>4)*8 + jj]
// One block per MT (16 A-rows = 8KB, contiguous in hist): straight 8KB LDS copy,
// then contiguous 16B short8 writes (32B/thread). Makes proj's A-loads fully
// coalesced (was: 16 discontiguous 64B chunks per load instruction).
// ---------------------------------------------------------------------------
__global__ __launch_bounds__(256) void prep_a(const unsigned short* __restrict__ hist,
                                              unsigned short* __restrict__ afr) {
    __shared__ __align__(16) unsigned short tile[16 * 256];
    const int MT = blockIdx.x;       // 0..511
    const int tid = threadIdx.x;

    const uint4* src = (const uint4*)(hist + (size_t)MT * 16 * 256);
    uint4* dst = (uint4*)tile;
    dst[tid]       = src[tid];
    dst[tid + 256] = src[tid + 256];
    __syncthreads();

    #pragma unroll
    for (int i = 0; i < 2; ++i) {
        int s = tid * 2 + i;         // 0..511 = kc*64 + lane
        int kc = s >> 6, lane = s & 63;
        int quad = lane >> 4, l15 = lane & 15;
        const unsigned short* p = tile + l15 * 256 + kc * 32 + quad * 8;
        *(short8*)(afr + (((size_t)MT * 8 + kc) * 64 + lane) * 8) = *(const short8*)p;
    }
}

// ---------------------------------------------------------------------------
// gru_rec: 32 blocks (one batch row) x 512 threads (8 waves). UNCHANGED.
// ---------------------------------------------------------------------------
__global__ __launch_bounds__(512, 1) void gru_rec(
    const int* __restrict__ X, const float* __restrict__ H0,
    const float* __restrict__ Wxz, const float* __restrict__ Wxr,
    const float* __restrict__ Wxh,
    const float* __restrict__ bz, const float* __restrict__ br,
    const float* __restrict__ bh,
    const unsigned short* __restrict__ Wsw,
    unsigned short* __restrict__ hist,   // [STEPS*BATCH][HID] bf16
    float* __restrict__ h_final)         // [BATCH][HID] f32
{
    const int b = blockIdx.x;
    const int tid = threadIdx.x;
    const bool isA = tid < HID;
    const int j = isA ? tid : tid - HID;

    __shared__ __align__(16) unsigned short hbuf[HID];
    __shared__ __align__(16) unsigned short rhbuf[HID];
    __shared__ float part[HID];
    __shared__ float xrow[2][3][HID];
    __shared__ int Xl[STEPS];

    const uint4* wA = (const uint4*)Wsw + (size_t)(isA ? 0 : 1) * 32 * HID + j; // z or r
    const uint4* wH = (const uint4*)Wsw + (size_t)2 * 32 * HID + j;             // h

    float h_my = H0[b * HID + j];
    float bias = isA ? bz[j] : br[j];
    float bhj  = isA ? bh[j] : 0.0f;

    // ---- hoist loop-invariant weights into registers (static indexing only) ----
    uint4 wreg[32];          // full-K column of W_hz (A) / W_hr (B)
    #pragma unroll
    for (int i = 0; i < 32; ++i) wreg[i] = wA[i * HID];

    const int i0 = isA ? 0 : 16;
    uint4 whreg[16];         // K-half column of W_hh
    #pragma unroll
    for (int i = 0; i < 16; ++i) whreg[i] = wH[(i0 + i) * HID];

    if (isA) { hbuf[j] = f2bf(h_my); Xl[j] = X[b * STEPS + j]; }
    __syncthreads();

    {   // initial x-row gather for t=0
        int x0 = Xl[0];
        if (isA) {
            xrow[0][0][j] = Wxz[(size_t)x0 * HID + j];
            xrow[0][2][j] = Wxh[(size_t)x0 * HID + j];
        } else {
            xrow[0][1][j] = Wxr[(size_t)x0 * HID + j];
        }
    }
    __syncthreads();

    float z = 0.0f;

    for (int t = 0; t < STEPS; ++t) {
        const int cur = t & 1, nxt = cur ^ 1;

        // prefetch next step's x-projection rows (wraps harmlessly at t=255)
        const int xn = Xl[(t + 1) & (STEPS - 1)];
        float p0 = 0.f, p1 = 0.f;
        if (isA) {
            p0 = Wxz[(size_t)xn * HID + j];
            p1 = Wxh[(size_t)xn * HID + j];
        } else {
            p0 = Wxr[(size_t)xn * HID + j];
        }

        // z-gate (A) / r-gate (B): full-K dot over h pairs, weights from VGPRs
        float acc;
        {
            const uint4* hp = (const uint4*)hbuf;
            float a0 = 0.f, a1 = 0.f, a2 = 0.f, a3 = 0.f;
            #pragma unroll
            for (int i = 0; i < 32; ++i) {
                uint4 hv = hp[i];
                a0 = dot2(wreg[i].x, hv.x, a0);
                a1 = dot2(wreg[i].y, hv.y, a1);
                a2 = dot2(wreg[i].z, hv.z, a2);
                a3 = dot2(wreg[i].w, hv.w, a3);
            }
            acc = (a0 + a1) + (a2 + a3);
        }

        if (isA) {
            z = sigmoidf_(acc + xrow[cur][0][j] + bias);
            xrow[nxt][0][j] = p0;
            xrow[nxt][2][j] = p1;
        } else {
            float r = sigmoidf_(acc + xrow[cur][1][j] + bias);
            rhbuf[j] = f2bf(r * h_my);
            xrow[nxt][1][j] = p0;
        }
        __syncthreads();  // B1: rhbuf + xrow[nxt] published

        // h-gate: K split between groups (A: pairs 0..63, B: 64..127)
        float acch;
        {
            const uint4* rp = (const uint4*)rhbuf;
            float a0 = 0.f, a1 = 0.f, a2 = 0.f, a3 = 0.f;
            #pragma unroll
            for (int i = 0; i < 16; ++i) {
                uint4 hv = rp[i0 + i];
                a0 = dot2(whreg[i].x, hv.x, a0);
                a1 = dot2(whreg[i].y, hv.y, a1);
                a2 = dot2(whreg[i].z, hv.z, a2);
                a3 = dot2(whreg[i].w, hv.w, a3);
            }
            acch = (a0 + a1) + (a2 + a3);
        }
        if (!isA) part[j] = acch;
        __syncthreads();  // B2: h-gate partials published

        if (isA) {
            float hpre = acch + part[j] + xrow[cur][2][j] + bhj;
            float ht = tanhf_(hpre);
            float hn = z * h_my + (1.0f - z) * ht;
            h_my = hn;
            unsigned short hb = f2bf(hn);
            hbuf[j] = hb;
            hist[((size_t)t * BATCH + b) * HID + j] = hb;
        }
        __syncthreads();  // B3: hbuf published

        if (!isA) h_my = bf2f(hbuf[j]);  // B's h copy (bf16-rounded, used only for rh)
    }

    if (isA) h_final[b * HID + j] = h_my;
}

// ---------------------------------------------------------------------------
// proj: C[8192][10000] = A[8192][256](bf16) @ B[256][10000](bf16) + bq, f32 out
// MFMA 16x16x32, no LDS. Block: 256 thr (4 waves), BM=128 (8 m-tiles),
// 4 n-tiles per wave.
//  * A from pre-fragmented Afr (coalesced 1KB/instr; was 16 scattered 64B
//    chunks per instr straight from hist).
//  * SWAPPED operands -> lane holds 4 consecutive cols -> float4 stores.
//  * NON-TEMPORAL C stores: C is write-once; keep the 327MB stream out of L2
//    so the A/B working set stays resident.
//  * XCD-locality swizzle: each XCD owns 5 nb-columns x all 64 mb.
// ---------------------------------------------------------------------------
__global__ __launch_bounds__(256, 2) void proj(
    const unsigned short* __restrict__ Afr,  // [512][8][64][8]
    const unsigned short* __restrict__ Bfr,  // [625][8][64][8]
    const float* __restrict__ bq,
    float* __restrict__ C)
{
    const int tid  = threadIdx.x;
    const int wave = tid >> 6;
    const int lane = tid & 63;
    const int l15  = lane & 15;
    const int quad = lane >> 4;

    // XCD-aware decode: blocks on one XCD share a 5-nb B-slice, sweep mb.
    const int orig = blockIdx.x;        // 0..2559
    const int xcd  = orig & 7;
    const int idx  = orig >> 3;         // 0..319
    const int mb   = idx / 5;           // 0..63
    const int nb   = xcd * 5 + (idx % 5);  // 0..39

    const int m0 = mb * 128;
    const int nt0 = nb * 16 + wave * 4;

    floatx4 acc[8][4];
    #pragma unroll
    for (int i = 0; i < 8; ++i)
        #pragma unroll
        for (int q = 0; q < 4; ++q)
            acc[i][q] = (floatx4)0.0f;

    // clamp n-tiles for loads in the ragged tail block (stores are guarded)
    int ntc[4];
    #pragma unroll
    for (int q = 0; q < 4; ++q) {
        int nt = nt0 + q;
        ntc[q] = (nt < 625) ? nt : 624;
    }

    for (int kc = 0; kc < 8; ++kc) {
        short8 a[8];
        #pragma unroll
        for (int mt = 0; mt < 8; ++mt) {
            const unsigned short* ap =
                Afr + (((size_t)(mb * 8 + mt) * 8 + kc) * 64 + lane) * 8;
            a[mt] = *(const short8*)ap;
        }
        short8 bfrg[4];
        #pragma unroll
        for (int q = 0; q < 4; ++q) {
            const unsigned short* bp =
                Bfr + ((((size_t)ntc[q] * 8 + kc) * 64) + lane) * 8;
            bfrg[q] = *(const short8*)bp;
        }
        // operands SWAPPED: lane holds C[m0+mt*16+l15][nt*16+quad*4 + r]
        #pragma unroll
        for (int mt = 0; mt < 8; ++mt)
            #pragma unroll
            for (int q = 0; q < 4; ++q)
                acc[mt][q] = __builtin_amdgcn_mfma_f32_16x16x32_bf16(
                    bfrg[q], a[mt], acc[mt][q], 0, 0, 0);
    }

    // epilogue: bias + non-temporal float4 stores (4 consecutive cols per lane)
    floatx4 bq4[4];
    #pragma unroll
    for (int q = 0; q < 4; ++q) {
        int nt = nt0 + q;
        bq4[q] = (nt < 625) ? *(const floatx4*)(bq + nt * 16 + quad * 4)
                            : (floatx4)0.0f;
    }
    #pragma unroll
    for (int mt = 0; mt < 8; ++mt) {
        const size_t rowoff = (size_t)(m0 + mt * 16 + l15) * VOCAB;
        #pragma unroll
        for (int q = 0; q < 4; ++q) {
            int nt = nt0 + q;
            if (nt >= 625) continue;
            floatx4 v = acc[mt][q] + bq4[q];
            __builtin_nontemporal_store(v, (floatx4*)(C + rowoff + nt * 16 + quad * 4));
        }
    }
}

// ---------------------------------------------------------------------------
extern "C" void kernel_launch(void* const* d_in, const int* in_sizes, int n_in,
                              void* d_out, int out_size, void* d_ws, size_t ws_size,
                              hipStream_t stream) {
    const int*   X   = (const int*)  d_in[0];
    const float* H0  = (const float*)d_in[1];
    const float* Wxz = (const float*)d_in[2];
    const float* Whz = (const float*)d_in[3];
    const float* bz  = (const float*)d_in[4];
    const float* Wxr = (const float*)d_in[5];
    const float* Whr = (const float*)d_in[6];
    const float* br  = (const float*)d_in[7];
    const float* Wxh = (const float*)d_in[8];
    const float* Whh = (const float*)d_in[9];
    const float* bh  = (const float*)d_in[10];
    const float* Whq = (const float*)d_in[11];
    const float* bq  = (const float*)d_in[12];

    float* out     = (float*)d_out;
    float* h_final = out + (size_t)STEPS * BATCH * VOCAB;

    // ws layout (ushorts): Wsw[196608] | Bfr[2560000] | hist[2097152] | Afr[2097152]
    //   = 13.9 MB
    unsigned short* wsw  = (unsigned short*)d_ws;
    unsigned short* bfr  = wsw + 196608;
    unsigned short* hist = bfr + 2560000;
    unsigned short* afr  = hist + 2097152;

    prep_w<<<dim3(3, 32), 256, 0, stream>>>(Whz, Whr, Whh, wsw);
    prep_b<<<dim3(40, 8), 256, 0, stream>>>(Whq, bfr);
    gru_rec<<<BATCH, 512, 0, stream>>>(X, H0, Wxz, Wxr, Wxh, bz, br, bh,
                                       wsw, hist, h_final);
    prep_a<<<512, 256, 0, stream>>>(hist, afr);
    proj<<<2560, 256, 0, stream>>>(afr, bfr, bq, out);
}